// Round 1
// baseline (529.647 us; speedup 1.0000x reference)
//
#include <hip/hip_runtime.h>
#include <stdint.h>
#include <math.h>

// DeeperGNN forward on MI355X.
// Pipeline: encoders (bf16 MFMA GEMM) -> per layer {preLN -> CSR online-softmax
// aggregation -> GEMM(256->512) -> LN512 -> GEMM(512->256, +residual)} -> LN -> head.
// f32 residual stream / softmax / LN stats; bf16 GEMM operands + edge encodings.

typedef __bf16 bf16x8 __attribute__((ext_vector_type(8)));
typedef __bf16 bf16x4 __attribute__((ext_vector_type(4)));
typedef __bf16 bf16x2 __attribute__((ext_vector_type(2)));
typedef float  f32x4  __attribute__((ext_vector_type(4)));

constexpr int NN   = 16384;   // nodes
constexpr int NE   = 131072;  // edges
constexpr int DIN  = 128;
constexpr int DE   = 64;
constexpr int HD   = 256;
constexpr int HD2  = 512;

__device__ __forceinline__ void gl_lds16(const __bf16* g, __bf16* l) {
  __builtin_amdgcn_global_load_lds((const __attribute__((address_space(1))) void*)g,
                                   (__attribute__((address_space(3))) void*)l, 16, 0, 0);
}

// ---------------- CSR build ----------------
__global__ void k_hist(const int* __restrict__ dst, int* __restrict__ deg) {
  int e = blockIdx.x * 256 + threadIdx.x;
  if (e < NE) atomicAdd(&deg[dst[e]], 1);
}

__global__ __launch_bounds__(1024) void k_scan(const int* __restrict__ deg,
                                               int* __restrict__ row_start) {
  __shared__ int part[1024];
  const int t = threadIdx.x;
  const int base = t * 16;
  int loc[16];
  int s = 0;
  #pragma unroll
  for (int i = 0; i < 16; i++) { loc[i] = s; s += deg[base + i]; }
  part[t] = s;
  __syncthreads();
  for (int off = 1; off < 1024; off <<= 1) {
    int v = (t >= off) ? part[t - off] : 0;
    __syncthreads();
    part[t] += v;
    __syncthreads();
  }
  const int excl = (t == 0) ? 0 : part[t - 1];
  #pragma unroll
  for (int i = 0; i < 16; i++) row_start[base + i] = excl + loc[i];
}

__global__ void k_scatter(const int* __restrict__ src, const int* __restrict__ dst,
                          const int* __restrict__ row_start, int* __restrict__ cursor,
                          int* __restrict__ csr_eid, int* __restrict__ csr_src) {
  int e = blockIdx.x * 256 + threadIdx.x;
  if (e >= NE) return;
  const int d = dst[e];
  const int p = atomicAdd(&cursor[d], 1);
  const int pos = row_start[d] + p;
  csr_eid[pos] = e;
  csr_src[pos] = src[e];
}

// ---------------- weight prep ----------------
// transpose+convert: w [B][K][Nn] f32 -> wT [B][Nn][K] bf16
__global__ void k_wt(const float* __restrict__ w, __bf16* __restrict__ wT,
                     int K, int Nn, int B) {
  int i = blockIdx.x * 256 + threadIdx.x;
  if (i >= B * K * Nn) return;
  const int l = i / (K * Nn);
  const int r = i % (K * Nn);
  const int k = r / Nn, n = r % Nn;
  wT[(size_t)l * K * Nn + (size_t)n * K + k] = (__bf16)w[i];
}

__global__ void k_cvt(const float* __restrict__ a, __bf16* __restrict__ o, int n4) {
  int i = blockIdx.x * 256 + threadIdx.x;
  if (i >= n4) return;
  const float4 v = ((const float4*)a)[i];
  bf16x4 r;
  r.x = (__bf16)v.x; r.y = (__bf16)v.y; r.z = (__bf16)v.z; r.w = (__bf16)v.w;
  ((bf16x4*)o)[i] = r;
}

// ---------------- MFMA GEMM: C[M,Nn] = A[M,K](bf16) * BT[Nn,K](bf16) + bias (+R) ----
// 128x128 tile, 4 waves x (64x64), BK=32. LDS layout [kslice][row][8] (16B units).
template <int RES, int OBF>
__global__ __launch_bounds__(256, 2)
void k_gemm(const __bf16* __restrict__ A, const __bf16* __restrict__ BT,
            const float* __restrict__ bias, const float* __restrict__ R,
            void* __restrict__ C, int M, int Nn, int K) {
  __shared__ __bf16 lsA[4096];
  __shared__ __bf16 lsB[4096];
  const int tid  = threadIdx.x;
  const int lane = tid & 63;
  const int wave = tid >> 6;
  const int ntn  = Nn >> 7;
  const int bm   = (int)blockIdx.x / ntn;
  const int bn   = (int)blockIdx.x % ntn;
  const size_t row0 = (size_t)bm * 128, col0 = (size_t)bn * 128;
  const int wr = (wave >> 1) * 64, wc = (wave & 1) * 64;
  const int ks = lane >> 4, fr = lane & 15;

  f32x4 acc[4][4] = {};

  const int s1 = tid, s2 = tid + 256;
  const int r1 = s1 & 127, ks1 = s1 >> 7;
  const int r2 = s2 & 127, ks2 = s2 >> 7;

  for (int k0 = 0; k0 < K; k0 += 32) {
    gl_lds16(A  + (row0 + r1) * K + k0 + ks1 * 8, &lsA[s1 * 8]);
    gl_lds16(A  + (row0 + r2) * K + k0 + ks2 * 8, &lsA[s2 * 8]);
    gl_lds16(BT + (col0 + r1) * K + k0 + ks1 * 8, &lsB[s1 * 8]);
    gl_lds16(BT + (col0 + r2) * K + k0 + ks2 * 8, &lsB[s2 * 8]);
    __syncthreads();
    bf16x8 af[4], bfr[4];
    #pragma unroll
    for (int m = 0; m < 4; m++) af[m]  = *(const bf16x8*)&lsA[(ks * 128 + wr + m * 16 + fr) * 8];
    #pragma unroll
    for (int n = 0; n < 4; n++) bfr[n] = *(const bf16x8*)&lsB[(ks * 128 + wc + n * 16 + fr) * 8];
    #pragma unroll
    for (int m = 0; m < 4; m++)
      #pragma unroll
      for (int n = 0; n < 4; n++)
        acc[m][n] = __builtin_amdgcn_mfma_f32_16x16x32_bf16(af[m], bfr[n], acc[m][n], 0, 0, 0);
    __syncthreads();
  }

  const int fq = lane >> 4;
  #pragma unroll
  for (int m = 0; m < 4; m++) {
    #pragma unroll
    for (int n = 0; n < 4; n++) {
      const size_t gcol = col0 + wc + n * 16 + fr;
      const float bv = bias[gcol];
      #pragma unroll
      for (int r = 0; r < 4; r++) {
        const size_t grow = row0 + wr + m * 16 + fq * 4 + r;
        float v = acc[m][n][r] + bv;
        if (RES) v += R[grow * Nn + gcol];
        if (OBF) ((__bf16*)C)[grow * Nn + gcol] = (__bf16)v;
        else     ((float*)C)[grow * Nn + gcol] = v;
      }
    }
  }
}

// ---------------- per-dst-node online softmax aggregation ----------------
// out a1[node][f] = bf16( sum_j msg_j*alpha_j + z[node][f] )
__global__ __launch_bounds__(256)
void k_msg(const float* __restrict__ z, const __bf16* __restrict__ ebf,
           const int* __restrict__ row_start, const int* __restrict__ deg,
           const int* __restrict__ csr_eid, const int* __restrict__ csr_src,
           const float* __restrict__ tvec, int layer, __bf16* __restrict__ a1) {
  __shared__ int s_eid[256];
  __shared__ int s_src[256];
  const int node = blockIdx.x;
  const int f = threadIdx.x;
  const int st = row_start[node];
  const int dg = deg[node];
  const float t = tvec[layer];
  float mmax = -INFINITY, den = 0.f, agg = 0.f;
  for (int base = 0; base < dg; base += 256) {
    const int cnt = min(256, dg - base);
    if (f < cnt) { s_eid[f] = csr_eid[st + base + f]; s_src[f] = csr_src[st + base + f]; }
    __syncthreads();
    if (f == 0 && cnt > 1) {  // canonical order -> deterministic FP sums
      for (int a = 1; a < cnt; a++) {
        int ke = s_eid[a], kv = s_src[a], b = a - 1;
        while (b >= 0 && s_eid[b] > ke) { s_eid[b+1] = s_eid[b]; s_src[b+1] = s_src[b]; b--; }
        s_eid[b+1] = ke; s_src[b+1] = kv;
      }
    }
    __syncthreads();
    for (int j = 0; j < cnt; j++) {
      const int eid = s_eid[j], sn = s_src[j];
      float v = z[(size_t)sn * HD + f] + (float)ebf[(size_t)eid * HD + f];
      v = fmaxf(v, 0.f) + 1e-7f;
      const float m  = v * t;
      const float nm = fmaxf(mmax, m);
      const float sc = __expf(mmax - nm);
      const float ex = __expf(m - nm);
      den = den * sc + ex;
      agg = agg * sc + v * ex;
      mmax = nm;
    }
    __syncthreads();
  }
  const float res = (dg > 0) ? agg / (den + 1e-16f) : 0.f;
  a1[(size_t)node * HD + f] = (__bf16)(res + z[(size_t)node * HD + f]);
}

// ---------------- LN kernels ----------------
// z = relu(LN_256(h)) , f32 out. 4 rows/block, 64 lanes x float4 per row.
__global__ __launch_bounds__(256)
void k_prenorm(const float* __restrict__ h, const float* __restrict__ g,
               const float* __restrict__ b, float* __restrict__ z) {
  const int row  = blockIdx.x * 4 + (threadIdx.x >> 6);
  const int lane = threadIdx.x & 63;
  const float4 v = *(const float4*)&h[(size_t)row * HD + lane * 4];
  float s = v.x + v.y + v.z + v.w;
  for (int o = 1; o < 64; o <<= 1) s += __shfl_xor(s, o);
  const float mu = s * (1.f / HD);
  const float dx = v.x - mu, dy = v.y - mu, dz = v.z - mu, dw = v.w - mu;
  float q = dx * dx + dy * dy + dz * dz + dw * dw;
  for (int o = 1; o < 64; o <<= 1) q += __shfl_xor(q, o);
  const float inv = rsqrtf(q * (1.f / HD) + 1e-5f);
  const float4 gv = *(const float4*)&g[lane * 4];
  const float4 bv = *(const float4*)&b[lane * 4];
  float4 r;
  r.x = fmaxf(dx * inv * gv.x + bv.x, 0.f);
  r.y = fmaxf(dy * inv * gv.y + bv.y, 0.f);
  r.z = fmaxf(dz * inv * gv.z + bv.z, 0.f);
  r.w = fmaxf(dw * inv * gv.w + bv.w, 0.f);
  *(float4*)&z[(size_t)row * HD + lane * 4] = r;
}

// a2 = bf16(relu(LN_512(c1))), one row per 256-thread block (float2/thread).
__global__ __launch_bounds__(256)
void k_ln512(const float* __restrict__ c1, const float* __restrict__ g,
             const float* __restrict__ b, __bf16* __restrict__ a2) {
  __shared__ float wsum[4];
  const int row = blockIdx.x;
  const int t = threadIdx.x, lane = t & 63, w = t >> 6;
  const float2 v = *(const float2*)&c1[(size_t)row * HD2 + t * 2];
  float s = v.x + v.y;
  for (int o = 1; o < 64; o <<= 1) s += __shfl_xor(s, o);
  if (lane == 0) wsum[w] = s;
  __syncthreads();
  const float mu = (wsum[0] + wsum[1] + wsum[2] + wsum[3]) * (1.f / HD2);
  const float dx = v.x - mu, dy = v.y - mu;
  float q = dx * dx + dy * dy;
  for (int o = 1; o < 64; o <<= 1) q += __shfl_xor(q, o);
  __syncthreads();
  if (lane == 0) wsum[w] = q;
  __syncthreads();
  const float inv = rsqrtf((wsum[0] + wsum[1] + wsum[2] + wsum[3]) * (1.f / HD2) + 1e-5f);
  const float2 gv = *(const float2*)&g[t * 2];
  const float2 bv = *(const float2*)&b[t * 2];
  bf16x2 r;
  r.x = (__bf16)fmaxf(dx * inv * gv.x + bv.x, 0.f);
  r.y = (__bf16)fmaxf(dy * inv * gv.y + bv.y, 0.f);
  *(bf16x2*)&a2[(size_t)row * HD2 + t * 2] = r;
}

// ---------------- head: out = relu(LN_256(h)) @ lin_w + lin_b ----------------
__global__ __launch_bounds__(256)
void k_head(const float* __restrict__ h, const float* __restrict__ g,
            const float* __restrict__ b, const float* __restrict__ lw,
            const float* __restrict__ lb, float* __restrict__ out) {
  __shared__ float sf[256];
  __shared__ float wsum[4];
  __shared__ float red[16][17];
  const int row = blockIdx.x, t = threadIdx.x, lane = t & 63, w = t >> 6;
  const float v = h[(size_t)row * HD + t];
  float s = v;
  for (int o = 1; o < 64; o <<= 1) s += __shfl_xor(s, o);
  if (lane == 0) wsum[w] = s;
  __syncthreads();
  const float mu = (wsum[0] + wsum[1] + wsum[2] + wsum[3]) * (1.f / HD);
  const float d = v - mu;
  float q = d * d;
  for (int o = 1; o < 64; o <<= 1) q += __shfl_xor(q, o);
  __syncthreads();
  if (lane == 0) wsum[w] = q;
  __syncthreads();
  const float var = (wsum[0] + wsum[1] + wsum[2] + wsum[3]) * (1.f / HD);
  sf[t] = fmaxf(d * rsqrtf(var + 1e-5f) * g[t] + b[t], 0.f);
  __syncthreads();
  const int o16 = t & 15, gr = t >> 4;
  float p = 0.f;
  #pragma unroll
  for (int j = 0; j < 16; j++) { const int ff = gr * 16 + j; p += sf[ff] * lw[ff * 16 + o16]; }
  red[gr][o16] = p;
  __syncthreads();
  if (t < 16) {
    float s2 = lb[t];
    #pragma unroll
    for (int gi = 0; gi < 16; gi++) s2 += red[gi][t];
    out[(size_t)row * 16 + t] = s2;
  }
}

// ---------------- host launch ----------------
extern "C" void kernel_launch(void* const* d_in, const int* in_sizes, int n_in,
                              void* d_out, int out_size, void* d_ws, size_t ws_size,
                              hipStream_t stream) {
  const float* x     = (const float*)d_in[0];
  const int*   ei    = (const int*)d_in[1];
  const float* ea    = (const float*)d_in[2];
  const float* enc_w = (const float*)d_in[3];
  const float* enc_b = (const float*)d_in[4];
  const float* ee_w  = (const float*)d_in[5];
  const float* ee_b  = (const float*)d_in[6];
  const float* w1    = (const float*)d_in[7];
  const float* b1    = (const float*)d_in[8];
  const float* lng   = (const float*)d_in[9];
  const float* lnb   = (const float*)d_in[10];
  const float* w2    = (const float*)d_in[11];
  const float* b2    = (const float*)d_in[12];
  const float* tvec  = (const float*)d_in[13];
  const float* ng    = (const float*)d_in[14];
  const float* nb    = (const float*)d_in[15];
  const float* lin_w = (const float*)d_in[16];
  const float* lin_b = (const float*)d_in[17];

  uint8_t* p = (uint8_t*)d_ws;
  auto alloc = [&](size_t bytes) { uint8_t* r = p; p += (bytes + 255) & ~(size_t)255; return r; };
  __bf16* e_bf   = (__bf16*)alloc((size_t)NE * HD * 2);
  float*  h      = (float*) alloc((size_t)NN * HD * 4);
  float*  z      = (float*) alloc((size_t)NN * HD * 4);
  __bf16* a1     = (__bf16*)alloc((size_t)NN * HD * 2);
  float*  c1     = (float*) alloc((size_t)NN * HD2 * 4);
  __bf16* a2     = (__bf16*)alloc((size_t)NN * HD2 * 2);
  __bf16* xbf    = (__bf16*)alloc((size_t)NN * DIN * 2);
  __bf16* eabf   = (__bf16*)alloc((size_t)NE * DE * 2);
  __bf16* enc_wT = (__bf16*)alloc((size_t)HD * DIN * 2);
  __bf16* ee_wT  = (__bf16*)alloc((size_t)HD * DE * 2);
  __bf16* w1T    = (__bf16*)alloc((size_t)4 * HD2 * HD * 2);
  __bf16* w2T    = (__bf16*)alloc((size_t)4 * HD * HD2 * 2);
  int* deg       = (int*)alloc((size_t)NN * 4);
  int* row_start = (int*)alloc((size_t)NN * 4);
  int* cursor    = (int*)alloc((size_t)NN * 4);
  int* csr_eid   = (int*)alloc((size_t)NE * 4);
  int* csr_src   = (int*)alloc((size_t)NE * 4);

  const int* srcp = ei;
  const int* dstp = ei + NE;

  hipMemsetAsync(deg, 0, (size_t)NN * 4, stream);
  hipMemsetAsync(cursor, 0, (size_t)NN * 4, stream);
  k_hist<<<NE / 256, 256, 0, stream>>>(dstp, deg);
  k_scan<<<1, 1024, 0, stream>>>(deg, row_start);
  k_scatter<<<NE / 256, 256, 0, stream>>>(srcp, dstp, row_start, cursor, csr_eid, csr_src);

  k_wt<<<(DIN * HD + 255) / 256, 256, 0, stream>>>(enc_w, enc_wT, DIN, HD, 1);
  k_wt<<<(DE * HD + 255) / 256, 256, 0, stream>>>(ee_w, ee_wT, DE, HD, 1);
  k_wt<<<(4 * HD * HD2 + 255) / 256, 256, 0, stream>>>(w1, w1T, HD, HD2, 4);
  k_wt<<<(4 * HD2 * HD + 255) / 256, 256, 0, stream>>>(w2, w2T, HD2, HD, 4);
  k_cvt<<<(NN * DIN / 4 + 255) / 256, 256, 0, stream>>>(x, xbf, NN * DIN / 4);
  k_cvt<<<(NE * DE / 4 + 255) / 256, 256, 0, stream>>>(ea, eabf, NE * DE / 4);

  // node encoder: h = x @ enc_w + enc_b   [16384,256] f32
  k_gemm<0, 0><<<(NN / 128) * (HD / 128), 256, 0, stream>>>(xbf, enc_wT, enc_b, nullptr,
                                                            (void*)h, NN, HD, DIN);
  // edge encoder: e = ea @ ee_w + ee_b    [131072,256] bf16
  k_gemm<0, 1><<<(NE / 128) * (HD / 128), 256, 0, stream>>>(eabf, ee_wT, ee_b, nullptr,
                                                            (void*)e_bf, NE, HD, DE);

  for (int i = 0; i < 4; i++) {
    const float* zin;
    if (i > 0) {
      k_prenorm<<<NN / 4, 256, 0, stream>>>(h, ng + i * HD, nb + i * HD, z);
      zin = z;
    } else {
      zin = h;
    }
    k_msg<<<NN, 256, 0, stream>>>(zin, e_bf, row_start, deg, csr_eid, csr_src, tvec, i, a1);
    k_gemm<0, 0><<<(NN / 128) * (HD2 / 128), 256, 0, stream>>>(
        a1, w1T + (size_t)i * HD2 * HD, b1 + i * HD2, nullptr, (void*)c1, NN, HD2, HD);
    k_ln512<<<NN, 256, 0, stream>>>(c1, lng + i * HD2, lnb + i * HD2, a2);
    if (i == 0)
      k_gemm<0, 0><<<(NN / 128) * (HD / 128), 256, 0, stream>>>(
          a2, w2T + (size_t)i * HD * HD2, b2 + i * HD, nullptr, (void*)h, NN, HD, HD2);
    else
      k_gemm<1, 0><<<(NN / 128) * (HD / 128), 256, 0, stream>>>(
          a2, w2T + (size_t)i * HD * HD2, b2 + i * HD, h, (void*)h, NN, HD, HD2);
  }

  k_head<<<NN, 256, 0, stream>>>(h, ng, nb, lin_w, lin_b, (float*)d_out);
}

// Round 2
// 429.816 us; speedup vs baseline: 1.2323x; 1.2323x over previous
//
#include <hip/hip_runtime.h>
#include <stdint.h>
#include <math.h>

// DeeperGNN forward on MI355X.
// encoders (bf16 MFMA GEMM) -> per layer {preLN(bf16 out) -> wave-per-node
// softmax aggregation (no-max online exp, CSR sorted once) -> GEMM(256->512,bf16 out)
// -> LN512 -> GEMM(512->256,+residual f32)} -> LN -> head.

typedef __bf16 bf16x8 __attribute__((ext_vector_type(8)));
typedef __bf16 bf16x4 __attribute__((ext_vector_type(4)));
typedef __bf16 bf16x2 __attribute__((ext_vector_type(2)));
typedef float  f32x4  __attribute__((ext_vector_type(4)));

constexpr int NN   = 16384;   // nodes
constexpr int NE   = 131072;  // edges
constexpr int DIN  = 128;
constexpr int DE   = 64;
constexpr int HD   = 256;
constexpr int HD2  = 512;

__device__ __forceinline__ void gl_lds16(const __bf16* g, __bf16* l) {
  __builtin_amdgcn_global_load_lds((const __attribute__((address_space(1))) void*)g,
                                   (__attribute__((address_space(3))) void*)l, 16, 0, 0);
}

// ---------------- CSR build ----------------
__global__ void k_hist(const int* __restrict__ dst, int* __restrict__ deg) {
  int e = blockIdx.x * 256 + threadIdx.x;
  if (e < NE) atomicAdd(&deg[dst[e]], 1);
}

__global__ __launch_bounds__(1024) void k_scan(const int* __restrict__ deg,
                                               int* __restrict__ row_start) {
  __shared__ int part[1024];
  const int t = threadIdx.x;
  const int base = t * 16;
  int loc[16];
  int s = 0;
  #pragma unroll
  for (int i = 0; i < 16; i++) { loc[i] = s; s += deg[base + i]; }
  part[t] = s;
  __syncthreads();
  for (int off = 1; off < 1024; off <<= 1) {
    int v = (t >= off) ? part[t - off] : 0;
    __syncthreads();
    part[t] += v;
    __syncthreads();
  }
  const int excl = (t == 0) ? 0 : part[t - 1];
  #pragma unroll
  for (int i = 0; i < 16; i++) row_start[base + i] = excl + loc[i];
}

__global__ void k_scatter(const int* __restrict__ src, const int* __restrict__ dst,
                          const int* __restrict__ row_start, int* __restrict__ cursor,
                          int2* __restrict__ csr_es) {
  int e = blockIdx.x * 256 + threadIdx.x;
  if (e >= NE) return;
  const int d = dst[e];
  const int p = atomicAdd(&cursor[d], 1);
  csr_es[row_start[d] + p] = make_int2(e, src[e]);
}

// canonical per-node eid-order (determinism); one thread per node, deg ~8
__global__ void k_sort(const int* __restrict__ row_start, const int* __restrict__ deg,
                       int2* __restrict__ csr_es) {
  int n = blockIdx.x * 256 + threadIdx.x;
  if (n >= NN) return;
  const int st = row_start[n], dg = deg[n];
  for (int a = 1; a < dg; a++) {
    int2 k = csr_es[st + a];
    int b = a - 1;
    while (b >= 0 && csr_es[st + b].x > k.x) { csr_es[st + b + 1] = csr_es[st + b]; b--; }
    csr_es[st + b + 1] = k;
  }
}

// ---------------- weight prep ----------------
__global__ void k_wt(const float* __restrict__ w, __bf16* __restrict__ wT,
                     int K, int Nn, int B) {
  int i = blockIdx.x * 256 + threadIdx.x;
  if (i >= B * K * Nn) return;
  const int l = i / (K * Nn);
  const int r = i % (K * Nn);
  const int k = r / Nn, n = r % Nn;
  wT[(size_t)l * K * Nn + (size_t)n * K + k] = (__bf16)w[i];
}

__global__ void k_cvt(const float* __restrict__ a, __bf16* __restrict__ o, int n4) {
  int i = blockIdx.x * 256 + threadIdx.x;
  if (i >= n4) return;
  const float4 v = ((const float4*)a)[i];
  bf16x4 r;
  r[0] = (__bf16)v.x; r[1] = (__bf16)v.y; r[2] = (__bf16)v.z; r[3] = (__bf16)v.w;
  ((bf16x4*)o)[i] = r;
}

// ---------------- MFMA GEMM: C[M,Nn] = A[M,K](bf16) * BT[Nn,K](bf16) + bias (+R) ----
// 128x128 tile, 4 waves x (64x64), BK=32. OBF: 0=f32, 1=bf16, 2=f32 C + bf16 C2.
template <int RES, int OBF>
__global__ __launch_bounds__(256, 2)
void k_gemm(const __bf16* __restrict__ A, const __bf16* __restrict__ BT,
            const float* __restrict__ bias, const float* __restrict__ R,
            void* __restrict__ C, __bf16* __restrict__ C2, int M, int Nn, int K) {
  __shared__ __bf16 lsA[4096];
  __shared__ __bf16 lsB[4096];
  const int tid  = threadIdx.x;
  const int lane = tid & 63;
  const int wave = tid >> 6;
  const int ntn  = Nn >> 7;
  const int bm   = (int)blockIdx.x / ntn;
  const int bn   = (int)blockIdx.x % ntn;
  const size_t row0 = (size_t)bm * 128, col0 = (size_t)bn * 128;
  const int wr = (wave >> 1) * 64, wc = (wave & 1) * 64;
  const int ks = lane >> 4, fr = lane & 15;

  f32x4 acc[4][4] = {};

  const int s1 = tid, s2 = tid + 256;
  const int r1 = s1 & 127, ks1 = s1 >> 7;
  const int r2 = s2 & 127, ks2 = s2 >> 7;

  for (int k0 = 0; k0 < K; k0 += 32) {
    gl_lds16(A  + (row0 + r1) * K + k0 + ks1 * 8, &lsA[s1 * 8]);
    gl_lds16(A  + (row0 + r2) * K + k0 + ks2 * 8, &lsA[s2 * 8]);
    gl_lds16(BT + (col0 + r1) * K + k0 + ks1 * 8, &lsB[s1 * 8]);
    gl_lds16(BT + (col0 + r2) * K + k0 + ks2 * 8, &lsB[s2 * 8]);
    __syncthreads();
    bf16x8 af[4], bfr[4];
    #pragma unroll
    for (int m = 0; m < 4; m++) af[m]  = *(const bf16x8*)&lsA[(ks * 128 + wr + m * 16 + fr) * 8];
    #pragma unroll
    for (int n = 0; n < 4; n++) bfr[n] = *(const bf16x8*)&lsB[(ks * 128 + wc + n * 16 + fr) * 8];
    #pragma unroll
    for (int m = 0; m < 4; m++)
      #pragma unroll
      for (int n = 0; n < 4; n++)
        acc[m][n] = __builtin_amdgcn_mfma_f32_16x16x32_bf16(af[m], bfr[n], acc[m][n], 0, 0, 0);
    __syncthreads();
  }

  const int fq = lane >> 4;
  #pragma unroll
  for (int m = 0; m < 4; m++) {
    #pragma unroll
    for (int n = 0; n < 4; n++) {
      const size_t gcol = col0 + wc + n * 16 + fr;
      const float bv = bias[gcol];
      #pragma unroll
      for (int r = 0; r < 4; r++) {
        const size_t grow = row0 + wr + m * 16 + fq * 4 + r;
        float v = acc[m][n][r] + bv;
        if (RES) v += R[grow * Nn + gcol];
        if (OBF == 1) ((__bf16*)C)[grow * Nn + gcol] = (__bf16)v;
        else          ((float*)C)[grow * Nn + gcol] = v;
        if (OBF == 2) C2[grow * Nn + gcol] = (__bf16)v;
      }
    }
  }
}

// ---------------- wave-per-node softmax aggregation ----------------
// a1[node][f] = bf16( sum_j msg_j*alpha_j + z[node][f] );  msg recomputed from
// bf16 z-gather + bf16 edge encodings; direct exp (inputs bounded, t=O(1)).
__global__ __launch_bounds__(256)
void k_msg(const __bf16* __restrict__ zb, const __bf16* __restrict__ ebf,
           const int* __restrict__ row_start, const int* __restrict__ deg,
           const int2* __restrict__ csr_es, const float* __restrict__ tvec,
           int layer, __bf16* __restrict__ a1) {
  const int wv   = __builtin_amdgcn_readfirstlane(threadIdx.x >> 6);
  const int lane = threadIdx.x & 63;
  const int node = blockIdx.x * 4 + wv;
  const int st = __builtin_amdgcn_readfirstlane(row_start[node]);
  const int dg = __builtin_amdgcn_readfirstlane(deg[node]);
  const float t = tvec[layer];
  const int f0 = lane * 4;

  int my_eid = 0, my_src = 0;
  if (lane < dg) { int2 pr = csr_es[st + lane]; my_eid = pr.x; my_src = pr.y; }

  float den[4] = {0.f, 0.f, 0.f, 0.f}, agg[4] = {0.f, 0.f, 0.f, 0.f};
  const int dmain = dg < 64 ? dg : 64;
  for (int j = 0; j < dmain; j++) {
    const int eid = __builtin_amdgcn_readlane(my_eid, j);
    const int sn  = __builtin_amdgcn_readlane(my_src, j);
    const bf16x4 zv = *(const bf16x4*)&zb[(size_t)sn * HD + f0];
    const bf16x4 ev = *(const bf16x4*)&ebf[(size_t)eid * HD + f0];
    #pragma unroll
    for (int q = 0; q < 4; q++) {
      const float m  = fmaxf((float)zv[q] + (float)ev[q], 0.f) + 1e-7f;
      const float ex = __expf(m * t);
      den[q] += ex;
      agg[q] += m * ex;
    }
  }
  for (int j = 64; j < dg; j++) {  // cold path, deg>64 never expected
    const int2 pr = csr_es[st + j];
    const bf16x4 zv = *(const bf16x4*)&zb[(size_t)pr.y * HD + f0];
    const bf16x4 ev = *(const bf16x4*)&ebf[(size_t)pr.x * HD + f0];
    #pragma unroll
    for (int q = 0; q < 4; q++) {
      const float m  = fmaxf((float)zv[q] + (float)ev[q], 0.f) + 1e-7f;
      const float ex = __expf(m * t);
      den[q] += ex;
      agg[q] += m * ex;
    }
  }
  const bf16x4 sv = *(const bf16x4*)&zb[(size_t)node * HD + f0];
  bf16x4 r;
  #pragma unroll
  for (int q = 0; q < 4; q++) {
    const float res = (dg > 0) ? agg[q] / (den[q] + 1e-16f) : 0.f;
    r[q] = (__bf16)(res + (float)sv[q]);
  }
  *(bf16x4*)&a1[(size_t)node * HD + f0] = r;
}

// ---------------- LN kernels ----------------
// zb = bf16(relu(LN_256(h))). 4 rows/block, 64 lanes x 4 feats.
__global__ __launch_bounds__(256)
void k_prenorm(const float* __restrict__ h, const float* __restrict__ g,
               const float* __restrict__ b, __bf16* __restrict__ zb) {
  const int row  = blockIdx.x * 4 + (threadIdx.x >> 6);
  const int lane = threadIdx.x & 63;
  const float4 v = *(const float4*)&h[(size_t)row * HD + lane * 4];
  float s = v.x + v.y + v.z + v.w;
  for (int o = 1; o < 64; o <<= 1) s += __shfl_xor(s, o);
  const float mu = s * (1.f / HD);
  const float dx = v.x - mu, dy = v.y - mu, dz = v.z - mu, dw = v.w - mu;
  float q = dx * dx + dy * dy + dz * dz + dw * dw;
  for (int o = 1; o < 64; o <<= 1) q += __shfl_xor(q, o);
  const float inv = rsqrtf(q * (1.f / HD) + 1e-5f);
  const float4 gv = *(const float4*)&g[lane * 4];
  const float4 bv = *(const float4*)&b[lane * 4];
  bf16x4 r;
  r[0] = (__bf16)fmaxf(dx * inv * gv.x + bv.x, 0.f);
  r[1] = (__bf16)fmaxf(dy * inv * gv.y + bv.y, 0.f);
  r[2] = (__bf16)fmaxf(dz * inv * gv.z + bv.z, 0.f);
  r[3] = (__bf16)fmaxf(dw * inv * gv.w + bv.w, 0.f);
  *(bf16x4*)&zb[(size_t)row * HD + lane * 4] = r;
}

// a2 = bf16(relu(LN_512(c1b))), 2 rows/block, 2 waves/row, bf16x4/lane.
__global__ __launch_bounds__(256)
void k_ln512(const __bf16* __restrict__ c1b, const float* __restrict__ g,
             const float* __restrict__ b, __bf16* __restrict__ a2) {
  __shared__ float sred[2][2][2];
  const int tid = threadIdx.x, lane = tid & 63, wv = tid >> 6;
  const int rib = wv >> 1, half = wv & 1;
  const int row = blockIdx.x * 2 + rib;
  const int idx = (half * 64 + lane) * 4;
  const bf16x4 v = *(const bf16x4*)&c1b[(size_t)row * HD2 + idx];
  const float x0 = (float)v[0], x1 = (float)v[1], x2 = (float)v[2], x3 = (float)v[3];
  float s = x0 + x1 + x2 + x3;
  for (int o = 1; o < 64; o <<= 1) s += __shfl_xor(s, o);
  if (lane == 0) sred[rib][half][0] = s;
  __syncthreads();
  const float mu = (sred[rib][0][0] + sred[rib][1][0]) * (1.f / HD2);
  const float d0 = x0 - mu, d1 = x1 - mu, d2 = x2 - mu, d3 = x3 - mu;
  float q = d0 * d0 + d1 * d1 + d2 * d2 + d3 * d3;
  for (int o = 1; o < 64; o <<= 1) q += __shfl_xor(q, o);
  if (lane == 0) sred[rib][half][1] = q;
  __syncthreads();
  const float inv = rsqrtf((sred[rib][0][1] + sred[rib][1][1]) * (1.f / HD2) + 1e-5f);
  const float4 gv = *(const float4*)&g[idx];
  const float4 bv = *(const float4*)&b[idx];
  bf16x4 r;
  r[0] = (__bf16)fmaxf(d0 * inv * gv.x + bv.x, 0.f);
  r[1] = (__bf16)fmaxf(d1 * inv * gv.y + bv.y, 0.f);
  r[2] = (__bf16)fmaxf(d2 * inv * gv.z + bv.z, 0.f);
  r[3] = (__bf16)fmaxf(d3 * inv * gv.w + bv.w, 0.f);
  *(bf16x4*)&a2[(size_t)row * HD2 + idx] = r;
}

// ---------------- head: out = relu(LN_256(h)) @ lin_w + lin_b ----------------
__global__ __launch_bounds__(256)
void k_head(const float* __restrict__ h, const float* __restrict__ g,
            const float* __restrict__ b, const float* __restrict__ lw,
            const float* __restrict__ lb, float* __restrict__ out) {
  __shared__ float sf[256];
  __shared__ float wsum[4];
  __shared__ float red[16][17];
  const int row = blockIdx.x, t = threadIdx.x, lane = t & 63, w = t >> 6;
  const float v = h[(size_t)row * HD + t];
  float s = v;
  for (int o = 1; o < 64; o <<= 1) s += __shfl_xor(s, o);
  if (lane == 0) wsum[w] = s;
  __syncthreads();
  const float mu = (wsum[0] + wsum[1] + wsum[2] + wsum[3]) * (1.f / HD);
  const float d = v - mu;
  float q = d * d;
  for (int o = 1; o < 64; o <<= 1) q += __shfl_xor(q, o);
  __syncthreads();
  if (lane == 0) wsum[w] = q;
  __syncthreads();
  const float var = (wsum[0] + wsum[1] + wsum[2] + wsum[3]) * (1.f / HD);
  sf[t] = fmaxf(d * rsqrtf(var + 1e-5f) * g[t] + b[t], 0.f);
  __syncthreads();
  const int o16 = t & 15, gr = t >> 4;
  float p = 0.f;
  #pragma unroll
  for (int j = 0; j < 16; j++) { const int ff = gr * 16 + j; p += sf[ff] * lw[ff * 16 + o16]; }
  red[gr][o16] = p;
  __syncthreads();
  if (t < 16) {
    float s2 = lb[t];
    #pragma unroll
    for (int gi = 0; gi < 16; gi++) s2 += red[gi][t];
    out[(size_t)row * 16 + t] = s2;
  }
}

// ---------------- host launch ----------------
extern "C" void kernel_launch(void* const* d_in, const int* in_sizes, int n_in,
                              void* d_out, int out_size, void* d_ws, size_t ws_size,
                              hipStream_t stream) {
  const float* x     = (const float*)d_in[0];
  const int*   ei    = (const int*)d_in[1];
  const float* ea    = (const float*)d_in[2];
  const float* enc_w = (const float*)d_in[3];
  const float* enc_b = (const float*)d_in[4];
  const float* ee_w  = (const float*)d_in[5];
  const float* ee_b  = (const float*)d_in[6];
  const float* w1    = (const float*)d_in[7];
  const float* b1    = (const float*)d_in[8];
  const float* lng   = (const float*)d_in[9];
  const float* lnb   = (const float*)d_in[10];
  const float* w2    = (const float*)d_in[11];
  const float* b2    = (const float*)d_in[12];
  const float* tvec  = (const float*)d_in[13];
  const float* ng    = (const float*)d_in[14];
  const float* nb    = (const float*)d_in[15];
  const float* lin_w = (const float*)d_in[16];
  const float* lin_b = (const float*)d_in[17];

  uint8_t* p = (uint8_t*)d_ws;
  auto alloc = [&](size_t bytes) { uint8_t* r = p; p += (bytes + 255) & ~(size_t)255; return r; };
  __bf16* e_bf   = (__bf16*)alloc((size_t)NE * HD * 2);
  float*  h      = (float*) alloc((size_t)NN * HD * 4);
  __bf16* hb     = (__bf16*)alloc((size_t)NN * HD * 2);
  __bf16* zb     = (__bf16*)alloc((size_t)NN * HD * 2);
  __bf16* a1     = (__bf16*)alloc((size_t)NN * HD * 2);
  __bf16* c1b    = (__bf16*)alloc((size_t)NN * HD2 * 2);
  __bf16* a2     = (__bf16*)alloc((size_t)NN * HD2 * 2);
  __bf16* xbf    = (__bf16*)alloc((size_t)NN * DIN * 2);
  __bf16* eabf   = (__bf16*)alloc((size_t)NE * DE * 2);
  __bf16* enc_wT = (__bf16*)alloc((size_t)HD * DIN * 2);
  __bf16* ee_wT  = (__bf16*)alloc((size_t)HD * DE * 2);
  __bf16* w1T    = (__bf16*)alloc((size_t)4 * HD2 * HD * 2);
  __bf16* w2T    = (__bf16*)alloc((size_t)4 * HD * HD2 * 2);
  int* deg       = (int*)alloc((size_t)NN * 4);
  int* row_start = (int*)alloc((size_t)NN * 4);
  int* cursor    = (int*)alloc((size_t)NN * 4);
  int2* csr_es   = (int2*)alloc((size_t)NE * 8);

  const int* srcp = ei;
  const int* dstp = ei + NE;

  hipMemsetAsync(deg, 0, (size_t)NN * 4, stream);
  hipMemsetAsync(cursor, 0, (size_t)NN * 4, stream);
  k_hist<<<NE / 256, 256, 0, stream>>>(dstp, deg);
  k_scan<<<1, 1024, 0, stream>>>(deg, row_start);
  k_scatter<<<NE / 256, 256, 0, stream>>>(srcp, dstp, row_start, cursor, csr_es);
  k_sort<<<NN / 256, 256, 0, stream>>>(row_start, deg, csr_es);

  k_wt<<<(DIN * HD + 255) / 256, 256, 0, stream>>>(enc_w, enc_wT, DIN, HD, 1);
  k_wt<<<(DE * HD + 255) / 256, 256, 0, stream>>>(ee_w, ee_wT, DE, HD, 1);
  k_wt<<<(4 * HD * HD2 + 255) / 256, 256, 0, stream>>>(w1, w1T, HD, HD2, 4);
  k_wt<<<(4 * HD2 * HD + 255) / 256, 256, 0, stream>>>(w2, w2T, HD2, HD, 4);
  k_cvt<<<(NN * DIN / 4 + 255) / 256, 256, 0, stream>>>(x, xbf, NN * DIN / 4);
  k_cvt<<<(NE * DE / 4 + 255) / 256, 256, 0, stream>>>(ea, eabf, NE * DE / 4);

  // node encoder: h(f32) + hb(bf16) = x @ enc_w + enc_b
  k_gemm<0, 2><<<(NN / 128) * (HD / 128), 256, 0, stream>>>(xbf, enc_wT, enc_b, nullptr,
                                                            (void*)h, hb, NN, HD, DIN);
  // edge encoder: e_bf = bf16(ea @ ee_w + ee_b)
  k_gemm<0, 1><<<(NE / 128) * (HD / 128), 256, 0, stream>>>(eabf, ee_wT, ee_b, nullptr,
                                                            (void*)e_bf, nullptr, NE, HD, DE);

  for (int i = 0; i < 4; i++) {
    const __bf16* zin;
    if (i > 0) {
      k_prenorm<<<NN / 4, 256, 0, stream>>>(h, ng + i * HD, nb + i * HD, zb);
      zin = zb;
    } else {
      zin = hb;
    }
    k_msg<<<NN / 4, 256, 0, stream>>>(zin, e_bf, row_start, deg, csr_es, tvec, i, a1);
    k_gemm<0, 1><<<(NN / 128) * (HD2 / 128), 256, 0, stream>>>(
        a1, w1T + (size_t)i * HD2 * HD, b1 + i * HD2, nullptr, (void*)c1b, nullptr, NN, HD2, HD);
    k_ln512<<<NN / 2, 256, 0, stream>>>(c1b, lng + i * HD2, lnb + i * HD2, a2);
    if (i == 0)
      k_gemm<0, 0><<<(NN / 128) * (HD / 128), 256, 0, stream>>>(
          a2, w2T + (size_t)i * HD * HD2, b2 + i * HD, nullptr, (void*)h, nullptr, NN, HD, HD2);
    else
      k_gemm<1, 0><<<(NN / 128) * (HD / 128), 256, 0, stream>>>(
          a2, w2T + (size_t)i * HD * HD2, b2 + i * HD, h, (void*)h, nullptr, NN, HD, HD2);
  }

  k_head<<<NN, 256, 0, stream>>>(h, ng, nb, lin_w, lin_b, (float*)d_out);
}

// Round 3
// 427.587 us; speedup vs baseline: 1.2387x; 1.0052x over previous
//
#include <hip/hip_runtime.h>
#include <stdint.h>
#include <math.h>

// DeeperGNN forward on MI355X.
// encoders (bf16 MFMA GEMM) -> per layer { wave-per-node softmax aggregation ->
// fused GEMM1(256->512)+LN512+ReLU -> fused GEMM2(512->256)+residual+LN256+ReLU }
// -> tiny head matmul. f32 residual/LN stats; bf16 GEMM operands + edge encodings.

typedef __bf16 bf16x8 __attribute__((ext_vector_type(8)));
typedef __bf16 bf16x4 __attribute__((ext_vector_type(4)));
typedef float  f32x4  __attribute__((ext_vector_type(4)));

constexpr int NN   = 16384;   // nodes
constexpr int NE   = 131072;  // edges
constexpr int DIN  = 128;
constexpr int DE   = 64;
constexpr int HD   = 256;
constexpr int HD2  = 512;

__device__ __forceinline__ void gl_lds16(const __bf16* g, __bf16* l) {
  __builtin_amdgcn_global_load_lds((const __attribute__((address_space(1))) void*)g,
                                   (__attribute__((address_space(3))) void*)l, 16, 0, 0);
}

// ---------------- CSR build ----------------
__global__ void k_hist(const int* __restrict__ dst, int* __restrict__ deg) {
  int e = blockIdx.x * 256 + threadIdx.x;
  if (e < NE) atomicAdd(&deg[dst[e]], 1);
}

__global__ __launch_bounds__(1024) void k_scan(const int* __restrict__ deg,
                                               int* __restrict__ row_start) {
  __shared__ int part[1024];
  const int t = threadIdx.x;
  const int base = t * 16;
  int loc[16];
  int s = 0;
  #pragma unroll
  for (int i = 0; i < 16; i++) { loc[i] = s; s += deg[base + i]; }
  part[t] = s;
  __syncthreads();
  for (int off = 1; off < 1024; off <<= 1) {
    int v = (t >= off) ? part[t - off] : 0;
    __syncthreads();
    part[t] += v;
    __syncthreads();
  }
  const int excl = (t == 0) ? 0 : part[t - 1];
  #pragma unroll
  for (int i = 0; i < 16; i++) row_start[base + i] = excl + loc[i];
}

__global__ void k_scatter(const int* __restrict__ src, const int* __restrict__ dst,
                          const int* __restrict__ row_start, int* __restrict__ cursor,
                          int2* __restrict__ csr_es) {
  int e = blockIdx.x * 256 + threadIdx.x;
  if (e >= NE) return;
  const int d = dst[e];
  const int p = atomicAdd(&cursor[d], 1);
  csr_es[row_start[d] + p] = make_int2(e, src[e]);
}

// canonical per-node eid-order (determinism); one thread per node, deg ~8
__global__ void k_sort(const int* __restrict__ row_start, const int* __restrict__ deg,
                       int2* __restrict__ csr_es) {
  int n = blockIdx.x * 256 + threadIdx.x;
  if (n >= NN) return;
  const int st = row_start[n], dg = deg[n];
  for (int a = 1; a < dg; a++) {
    int2 k = csr_es[st + a];
    int b = a - 1;
    while (b >= 0 && csr_es[st + b].x > k.x) { csr_es[st + b + 1] = csr_es[st + b]; b--; }
    csr_es[st + b + 1] = k;
  }
}

// ---------------- merged prep: weight transposes + input bf16 casts ----------------
__global__ void k_prep(const float* __restrict__ enc_w, const float* __restrict__ ee_w,
                       const float* __restrict__ w1, const float* __restrict__ w2,
                       const float* __restrict__ x, const float* __restrict__ ea,
                       __bf16* __restrict__ enc_wT, __bf16* __restrict__ ee_wT,
                       __bf16* __restrict__ w1T, __bf16* __restrict__ w2T,
                       __bf16* __restrict__ xbf, __bf16* __restrict__ eabf) {
  int i = blockIdx.x * 256 + threadIdx.x;
  const int S0 = DIN * HD, S1 = DE * HD, S2 = 4 * HD * HD2, S3 = 4 * HD2 * HD;
  const int S4 = NN * DIN / 4, S5 = NE * DE / 4;
  if (i < S0) { int k = i / HD, n = i % HD; enc_wT[n * DIN + k] = (__bf16)enc_w[i]; return; }
  i -= S0;
  if (i < S1) { int k = i / HD, n = i % HD; ee_wT[n * DE + k] = (__bf16)ee_w[i]; return; }
  i -= S1;
  if (i < S2) {
    int l = i / (HD * HD2), r = i % (HD * HD2), k = r / HD2, n = r % HD2;
    w1T[(size_t)l * HD * HD2 + (size_t)n * HD + k] = (__bf16)w1[i]; return;
  }
  i -= S2;
  if (i < S3) {
    int l = i / (HD2 * HD), r = i % (HD2 * HD), k = r / HD, n = r % HD;
    w2T[(size_t)l * HD2 * HD + (size_t)n * HD2 + k] = (__bf16)w2[i]; return;
  }
  i -= S3;
  if (i < S4) {
    float4 v = ((const float4*)x)[i];
    bf16x4 r; r[0] = (__bf16)v.x; r[1] = (__bf16)v.y; r[2] = (__bf16)v.z; r[3] = (__bf16)v.w;
    ((bf16x4*)xbf)[i] = r; return;
  }
  i -= S4;
  if (i < S5) {
    float4 v = ((const float4*)ea)[i];
    bf16x4 r; r[0] = (__bf16)v.x; r[1] = (__bf16)v.y; r[2] = (__bf16)v.z; r[3] = (__bf16)v.w;
    ((bf16x4*)eabf)[i] = r; return;
  }
}

// ---------------- encoder GEMM (128x128 tile): C = A*BT + bias ----------------
// OBF: 1=bf16 out, 2=f32 C + bf16 C2 dual write.
template <int OBF>
__global__ __launch_bounds__(256, 2)
void k_gemm(const __bf16* __restrict__ A, const __bf16* __restrict__ BT,
            const float* __restrict__ bias, void* __restrict__ C,
            __bf16* __restrict__ C2, int M, int Nn, int K) {
  __shared__ __bf16 lsA[4096];
  __shared__ __bf16 lsB[4096];
  const int tid  = threadIdx.x;
  const int lane = tid & 63;
  const int wave = tid >> 6;
  const int ntn  = Nn >> 7;
  const int bm   = (int)blockIdx.x / ntn;
  const int bn   = (int)blockIdx.x % ntn;
  const size_t row0 = (size_t)bm * 128, col0 = (size_t)bn * 128;
  const int wr = (wave >> 1) * 64, wc = (wave & 1) * 64;
  const int ks = lane >> 4, fr = lane & 15;

  f32x4 acc[4][4] = {};

  const int s1 = tid, s2 = tid + 256;
  const int r1 = s1 & 127, ks1 = s1 >> 7;
  const int r2 = s2 & 127, ks2 = s2 >> 7;

  for (int k0 = 0; k0 < K; k0 += 32) {
    gl_lds16(A  + (row0 + r1) * K + k0 + ks1 * 8, &lsA[s1 * 8]);
    gl_lds16(A  + (row0 + r2) * K + k0 + ks2 * 8, &lsA[s2 * 8]);
    gl_lds16(BT + (col0 + r1) * K + k0 + ks1 * 8, &lsB[s1 * 8]);
    gl_lds16(BT + (col0 + r2) * K + k0 + ks2 * 8, &lsB[s2 * 8]);
    __syncthreads();
    bf16x8 af[4], bfr[4];
    #pragma unroll
    for (int m = 0; m < 4; m++) af[m]  = *(const bf16x8*)&lsA[(ks * 128 + wr + m * 16 + fr) * 8];
    #pragma unroll
    for (int n = 0; n < 4; n++) bfr[n] = *(const bf16x8*)&lsB[(ks * 128 + wc + n * 16 + fr) * 8];
    #pragma unroll
    for (int m = 0; m < 4; m++)
      #pragma unroll
      for (int n = 0; n < 4; n++)
        acc[m][n] = __builtin_amdgcn_mfma_f32_16x16x32_bf16(af[m], bfr[n], acc[m][n], 0, 0, 0);
    __syncthreads();
  }

  const int fq = lane >> 4;
  #pragma unroll
  for (int m = 0; m < 4; m++) {
    #pragma unroll
    for (int n = 0; n < 4; n++) {
      const size_t gcol = col0 + wc + n * 16 + fr;
      const float bv = bias[gcol];
      #pragma unroll
      for (int r = 0; r < 4; r++) {
        const size_t grow = row0 + wr + m * 16 + fq * 4 + r;
        float v = acc[m][n][r] + bv;
        if (OBF == 1) ((__bf16*)C)[grow * Nn + gcol] = (__bf16)v;
        else          ((float*)C)[grow * Nn + gcol] = v;
        if (OBF == 2) C2[grow * Nn + gcol] = (__bf16)v;
      }
    }
  }
}

// ---------------- fused GEMM + LN + ReLU ----------------
// Tile: 64 rows x NCOLS (full N). 4 waves, each 64 x NCOLS/4. BK=32, double-buffered.
// Epilogue: v = acc + bias (+R); per-row LN over NCOLS; z_out = bf16(relu(LN*g+b));
// optionally h_out = v (f32).
template <int NCOLS, int RES, int WH>
__global__ __launch_bounds__(256, 1)
void k_fgemm(const __bf16* __restrict__ A, const __bf16* __restrict__ BT,
             const float* __restrict__ bias, const float* __restrict__ R,
             const float* __restrict__ gamma, const float* __restrict__ beta,
             float* __restrict__ h_out, __bf16* __restrict__ z_out, int K) {
  constexpr int NFR = NCOLS / 64;       // B fragments per wave
  constexpr int BCH = NCOLS * 4 / 256;  // B 16B-chunks per thread
  __shared__ __bf16 lsA[2][2048];
  __shared__ __bf16 lsB[2][NCOLS * 32];
  const int tid = threadIdx.x, lane = tid & 63, wv = tid >> 6;
  const int wc = wv * (NCOLS / 4);
  const int fq = lane >> 4, fr = lane & 15;
  const size_t row0 = (size_t)blockIdx.x * 64;

  f32x4 acc[4][NFR] = {};

  const int ra = tid & 63, ka = tid >> 6;

  const int nk = K / 32;
  // prologue stage
  {
    gl_lds16(A + (row0 + ra) * K + ka * 8, &lsA[0][tid * 8]);
    #pragma unroll
    for (int j = 0; j < BCH; j++) {
      const int c = j * 256 + tid;
      const int col = c % NCOLS, kb = c / NCOLS;
      gl_lds16(BT + (size_t)col * K + kb * 8, &lsB[0][c * 8]);
    }
  }
  __syncthreads();
  for (int t = 0; t < nk; t++) {
    const int cur = t & 1;
    if (t + 1 < nk) {
      const int k0 = (t + 1) * 32;
      gl_lds16(A + (row0 + ra) * K + k0 + ka * 8, &lsA[cur ^ 1][tid * 8]);
      #pragma unroll
      for (int j = 0; j < BCH; j++) {
        const int c = j * 256 + tid;
        const int col = c % NCOLS, kb = c / NCOLS;
        gl_lds16(BT + (size_t)col * K + k0 + kb * 8, &lsB[cur ^ 1][c * 8]);
      }
    }
    bf16x8 af[4], bfr[NFR];
    #pragma unroll
    for (int m = 0; m < 4; m++) af[m] = *(const bf16x8*)&lsA[cur][(fq * 64 + m * 16 + fr) * 8];
    #pragma unroll
    for (int n = 0; n < NFR; n++)
      bfr[n] = *(const bf16x8*)&lsB[cur][(fq * NCOLS + wc + n * 16 + fr) * 8];
    #pragma unroll
    for (int m = 0; m < 4; m++)
      #pragma unroll
      for (int n = 0; n < NFR; n++)
        acc[m][n] = __builtin_amdgcn_mfma_f32_16x16x32_bf16(af[m], bfr[n], acc[m][n], 0, 0, 0);
    __syncthreads();  // drains next-stage vmcnt + protects buffer reuse
  }

  // ---- epilogue: bias (+residual) ----
  #pragma unroll
  for (int m = 0; m < 4; m++)
    #pragma unroll
    for (int n = 0; n < NFR; n++) {
      const int col = wc + n * 16 + fr;
      const float bv = bias[col];
      #pragma unroll
      for (int rr = 0; rr < 4; rr++) {
        float v = acc[m][n][rr] + bv;
        if (RES) {
          const size_t row = row0 + m * 16 + fq * 4 + rr;
          v += R[row * NCOLS + col];
        }
        acc[m][n][rr] = v;
      }
    }

  // ---- per-row LN stats (sum, sumsq over NCOLS) ----
  float s1[4][4], s2[4][4];
  #pragma unroll
  for (int m = 0; m < 4; m++)
    #pragma unroll
    for (int rr = 0; rr < 4; rr++) {
      float a = 0.f, b = 0.f;
      #pragma unroll
      for (int n = 0; n < NFR; n++) { const float v = acc[m][n][rr]; a += v; b += v * v; }
      s1[m][rr] = a; s2[m][rr] = b;
    }
  #pragma unroll
  for (int st = 1; st < 16; st <<= 1) {
    #pragma unroll
    for (int m = 0; m < 4; m++)
      #pragma unroll
      for (int rr = 0; rr < 4; rr++) {
        s1[m][rr] += __shfl_xor(s1[m][rr], st);
        s2[m][rr] += __shfl_xor(s2[m][rr], st);
      }
  }
  float* ssum = (float*)&lsA[0][0];  // [4 waves][64 rows]
  float* ssq  = ssum + 256;
  float* mus  = ssq + 256;
  float* invs = mus + 64;
  if (fr == 0) {
    #pragma unroll
    for (int m = 0; m < 4; m++)
      #pragma unroll
      for (int rr = 0; rr < 4; rr++) {
        const int rl = m * 16 + fq * 4 + rr;
        ssum[wv * 64 + rl] = s1[m][rr];
        ssq[wv * 64 + rl]  = s2[m][rr];
      }
  }
  __syncthreads();
  if (tid < 64) {
    float su = 0.f, sq = 0.f;
    #pragma unroll
    for (int w = 0; w < 4; w++) { su += ssum[w * 64 + tid]; sq += ssq[w * 64 + tid]; }
    const float mu = su * (1.f / NCOLS);
    const float var = sq * (1.f / NCOLS) - mu * mu;
    mus[tid] = mu;
    invs[tid] = rsqrtf(var + 1e-5f);
  }
  __syncthreads();

  // ---- transform + write ----
  #pragma unroll
  for (int m = 0; m < 4; m++)
    #pragma unroll
    for (int rr = 0; rr < 4; rr++) {
      const int rl = m * 16 + fq * 4 + rr;
      const size_t row = row0 + rl;
      const float mu = mus[rl], iv = invs[rl];
      #pragma unroll
      for (int n = 0; n < NFR; n++) {
        const int col = wc + n * 16 + fr;
        const float v = acc[m][n][rr];
        if (WH) h_out[row * NCOLS + col] = v;
        const float z = fmaxf((v - mu) * iv * gamma[col] + beta[col], 0.f);
        z_out[row * NCOLS + col] = (__bf16)z;
      }
    }
}

// ---------------- wave-per-node softmax aggregation ----------------
__global__ __launch_bounds__(256)
void k_msg(const __bf16* __restrict__ zb, const __bf16* __restrict__ ebf,
           const int* __restrict__ row_start, const int* __restrict__ deg,
           const int2* __restrict__ csr_es, const float* __restrict__ tvec,
           int layer, __bf16* __restrict__ a1) {
  const int wv   = __builtin_amdgcn_readfirstlane(threadIdx.x >> 6);
  const int lane = threadIdx.x & 63;
  const int node = blockIdx.x * 4 + wv;
  const int st = __builtin_amdgcn_readfirstlane(row_start[node]);
  const int dg = __builtin_amdgcn_readfirstlane(deg[node]);
  const float t = tvec[layer];
  const int f0 = lane * 4;

  int my_eid = 0, my_src = 0;
  if (lane < dg) { int2 pr = csr_es[st + lane]; my_eid = pr.x; my_src = pr.y; }

  float den[4] = {0.f, 0.f, 0.f, 0.f}, agg[4] = {0.f, 0.f, 0.f, 0.f};
  const int dmain = dg < 64 ? dg : 64;
  for (int j = 0; j < dmain; j++) {
    const int eid = __builtin_amdgcn_readlane(my_eid, j);
    const int sn  = __builtin_amdgcn_readlane(my_src, j);
    const bf16x4 zv = *(const bf16x4*)&zb[(size_t)sn * HD + f0];
    const bf16x4 ev = *(const bf16x4*)&ebf[(size_t)eid * HD + f0];
    #pragma unroll
    for (int q = 0; q < 4; q++) {
      const float m  = fmaxf((float)zv[q] + (float)ev[q], 0.f) + 1e-7f;
      const float ex = __expf(m * t);
      den[q] += ex;
      agg[q] += m * ex;
    }
  }
  for (int j = 64; j < dg; j++) {  // cold path
    const int2 pr = csr_es[st + j];
    const bf16x4 zv = *(const bf16x4*)&zb[(size_t)pr.y * HD + f0];
    const bf16x4 ev = *(const bf16x4*)&ebf[(size_t)pr.x * HD + f0];
    #pragma unroll
    for (int q = 0; q < 4; q++) {
      const float m  = fmaxf((float)zv[q] + (float)ev[q], 0.f) + 1e-7f;
      const float ex = __expf(m * t);
      den[q] += ex;
      agg[q] += m * ex;
    }
  }
  const bf16x4 sv = *(const bf16x4*)&zb[(size_t)node * HD + f0];
  bf16x4 r;
  #pragma unroll
  for (int q = 0; q < 4; q++) {
    const float res = (dg > 0) ? agg[q] / (den[q] + 1e-16f) : 0.f;
    r[q] = (__bf16)(res + (float)sv[q]);
  }
  *(bf16x4*)&a1[(size_t)node * HD + f0] = r;
}

// ---------------- head: out = zb @ lin_w + lin_b (zb already relu(LN)) ----------------
__global__ __launch_bounds__(256)
void k_head(const __bf16* __restrict__ zb, const float* __restrict__ lw,
            const float* __restrict__ lb, float* __restrict__ out) {
  __shared__ float slw[256 * 16];     // [k][c]
  __shared__ __bf16 srow[16 * 256];
  const int t = threadIdx.x;
  const size_t row0 = (size_t)blockIdx.x * 16;
  #pragma unroll
  for (int j = 0; j < 16; j++) slw[j * 256 + t] = lw[j * 256 + t];
  #pragma unroll
  for (int j = 0; j < 2; j++) {
    const int c = j * 256 + t;
    ((bf16x8*)srow)[c] = ((const bf16x8*)(zb + row0 * 256))[c];
  }
  __syncthreads();
  const int rl = t >> 4, col = t & 15;
  float s = lb[col];
  for (int k0 = 0; k0 < 256; k0 += 8) {
    const bf16x8 zv = *(const bf16x8*)&srow[rl * 256 + k0];
    #pragma unroll
    for (int q = 0; q < 8; q++) s += (float)zv[q] * slw[(k0 + q) * 16 + col];
  }
  out[(row0 + rl) * 16 + col] = s;
}

// ---------------- host launch ----------------
extern "C" void kernel_launch(void* const* d_in, const int* in_sizes, int n_in,
                              void* d_out, int out_size, void* d_ws, size_t ws_size,
                              hipStream_t stream) {
  const float* x     = (const float*)d_in[0];
  const int*   ei    = (const int*)d_in[1];
  const float* ea    = (const float*)d_in[2];
  const float* enc_w = (const float*)d_in[3];
  const float* enc_b = (const float*)d_in[4];
  const float* ee_w  = (const float*)d_in[5];
  const float* ee_b  = (const float*)d_in[6];
  const float* w1    = (const float*)d_in[7];
  const float* b1    = (const float*)d_in[8];
  const float* lng   = (const float*)d_in[9];
  const float* lnb   = (const float*)d_in[10];
  const float* w2    = (const float*)d_in[11];
  const float* b2    = (const float*)d_in[12];
  const float* tvec  = (const float*)d_in[13];
  const float* ng    = (const float*)d_in[14];
  const float* nb    = (const float*)d_in[15];
  const float* lin_w = (const float*)d_in[16];
  const float* lin_b = (const float*)d_in[17];

  uint8_t* p = (uint8_t*)d_ws;
  auto alloc = [&](size_t bytes) { uint8_t* r = p; p += (bytes + 255) & ~(size_t)255; return r; };
  __bf16* e_bf   = (__bf16*)alloc((size_t)NE * HD * 2);
  float*  h      = (float*) alloc((size_t)NN * HD * 4);
  __bf16* hb     = (__bf16*)alloc((size_t)NN * HD * 2);
  __bf16* zb     = (__bf16*)alloc((size_t)NN * HD * 2);
  __bf16* a1     = (__bf16*)alloc((size_t)NN * HD * 2);
  __bf16* a2     = (__bf16*)alloc((size_t)NN * HD2 * 2);
  __bf16* xbf    = (__bf16*)alloc((size_t)NN * DIN * 2);
  __bf16* eabf   = (__bf16*)alloc((size_t)NE * DE * 2);
  __bf16* enc_wT = (__bf16*)alloc((size_t)HD * DIN * 2);
  __bf16* ee_wT  = (__bf16*)alloc((size_t)HD * DE * 2);
  __bf16* w1T    = (__bf16*)alloc((size_t)4 * HD2 * HD * 2);
  __bf16* w2T    = (__bf16*)alloc((size_t)4 * HD * HD2 * 2);
  int* deg       = (int*)alloc((size_t)NN * 4);
  int* cursor    = (int*)alloc((size_t)NN * 4);   // contiguous with deg -> one memset
  int* row_start = (int*)alloc((size_t)NN * 4);
  int2* csr_es   = (int2*)alloc((size_t)NE * 8);

  const int* srcp = ei;
  const int* dstp = ei + NE;

  hipMemsetAsync(deg, 0, (size_t)NN * 8, stream);  // deg + cursor
  k_hist<<<NE / 256, 256, 0, stream>>>(dstp, deg);
  k_scan<<<1, 1024, 0, stream>>>(deg, row_start);
  k_scatter<<<NE / 256, 256, 0, stream>>>(srcp, dstp, row_start, cursor, csr_es);
  k_sort<<<NN / 256, 256, 0, stream>>>(row_start, deg, csr_es);

  const int prep_total = DIN * HD + DE * HD + 4 * HD * HD2 + 4 * HD2 * HD +
                         NN * DIN / 4 + NE * DE / 4;
  k_prep<<<(prep_total + 255) / 256, 256, 0, stream>>>(enc_w, ee_w, w1, w2, x, ea,
                                                       enc_wT, ee_wT, w1T, w2T, xbf, eabf);

  // node encoder: h(f32) + hb(bf16) = x @ enc_w + enc_b
  k_gemm<2><<<(NN / 128) * (HD / 128), 256, 0, stream>>>(xbf, enc_wT, enc_b,
                                                         (void*)h, hb, NN, HD, DIN);
  // edge encoder: e_bf = bf16(ea @ ee_w + ee_b)
  k_gemm<1><<<(NE / 128) * (HD / 128), 256, 0, stream>>>(eabf, ee_wT, ee_b,
                                                         (void*)e_bf, nullptr, NE, HD, DE);

  for (int i = 0; i < 4; i++) {
    const __bf16* zin = (i == 0) ? hb : zb;
    k_msg<<<NN / 4, 256, 0, stream>>>(zin, e_bf, row_start, deg, csr_es, tvec, i, a1);
    // GEMM1 fused with LN512+ReLU -> a2
    k_fgemm<512, 0, 0><<<NN / 64, 256, 0, stream>>>(
        a1, w1T + (size_t)i * HD2 * HD, b1 + (size_t)i * HD2, nullptr,
        lng + (size_t)i * HD2, lnb + (size_t)i * HD2, nullptr, a2, HD);
    // GEMM2 fused with residual + LN256+ReLU -> h (f32, except last) + zb (next z)
    const int nidx = (i < 3) ? i + 1 : 0;
    const float* g = ng + (size_t)nidx * HD;
    const float* bveq = nb + (size_t)nidx * HD;
    if (i == 0)
      k_fgemm<256, 0, 1><<<NN / 64, 256, 0, stream>>>(
          a2, w2T + (size_t)i * HD * HD2, b2 + (size_t)i * HD, nullptr, g, bveq, h, zb, HD2);
    else if (i < 3)
      k_fgemm<256, 1, 1><<<NN / 64, 256, 0, stream>>>(
          a2, w2T + (size_t)i * HD * HD2, b2 + (size_t)i * HD, h, g, bveq, h, zb, HD2);
    else
      k_fgemm<256, 1, 0><<<NN / 64, 256, 0, stream>>>(
          a2, w2T + (size_t)i * HD * HD2, b2 + (size_t)i * HD, h, g, bveq, nullptr, zb, HD2);
  }

  k_head<<<NN / 16, 256, 0, stream>>>(zb, lin_w, lin_b, (float*)d_out);
}